// Round 2
// baseline (275.706 us; speedup 1.0000x reference)
//
#include <hip/hip_runtime.h>
#include <stdint.h>

#define NQ 64
#define ZNEAR 0.1f
#define ZFAR 1000.0f
#define FT 16   // fill tile
#define BMAX 8
#define GMAX 2048
#define GRID 640   // multiple of SUBG; >= 600 fill tiles
#define SUBG 8     // sub-barrier fan-in groups

// ---------------- wave reductions (64-lane) ----------------
__device__ __forceinline__ float wave_min_f(float v) {
    #pragma unroll
    for (int off = 1; off < 64; off <<= 1)
        v = fminf(v, __shfl_xor(v, off, 64));
    return v;
}
__device__ __forceinline__ float wave_max_f(float v) {
    #pragma unroll
    for (int off = 1; off < 64; off <<= 1)
        v = fmaxf(v, __shfl_xor(v, off, 64));
    return v;
}
// uint-ordered reductions (valid for positive floats reinterpreted as uint)
__device__ __forceinline__ unsigned wave_umin_u(unsigned v) {
    #pragma unroll
    for (int off = 1; off < 64; off <<= 1) {
        unsigned o = (unsigned)__shfl_xor((int)v, off, 64);
        v = (v < o) ? v : o;
    }
    return v;
}
__device__ __forceinline__ unsigned wave_umax_u(unsigned v) {
    #pragma unroll
    for (int off = 1; off < 64; off <<= 1) {
        unsigned o = (unsigned)__shfl_xor((int)v, off, 64);
        v = (v > o) ? v : o;
    }
    return v;
}

// ---------------- manual grid barrier (sense-reversal, 2-level) ----------------
// Device globals are zero-initialized at module load; the barrier restores all
// state (counters back to 0, sense flipped an even number of times per launch),
// so every launch starts from a consistent state. Requires all blocks resident
// (guaranteed by hipLaunchCooperativeKernel validation).
__device__ unsigned g_sub[SUBG * 32];   // one counter per 128 B
__device__ unsigned g_root[32];
__device__ unsigned g_sense[32];

__device__ __forceinline__ void grid_bar(int nblk) {
    __syncthreads();
    if (threadIdx.x == 0) {
        __threadfence();   // make this block's global writes visible device-wide
        unsigned s = __hip_atomic_load(&g_sense[0], __ATOMIC_ACQUIRE, __HIP_MEMORY_SCOPE_AGENT);
        int g = (int)(blockIdx.x & (SUBG - 1));
        int gs = nblk / SUBG;                     // nblk is a multiple of SUBG
        unsigned old = __hip_atomic_fetch_add(&g_sub[g * 32], 1u,
                                              __ATOMIC_ACQ_REL, __HIP_MEMORY_SCOPE_AGENT);
        if ((int)old == gs - 1) {
            // last in sub-group: reset sub-counter, arrive at root
            __hip_atomic_store(&g_sub[g * 32], 0u, __ATOMIC_RELAXED, __HIP_MEMORY_SCOPE_AGENT);
            unsigned rold = __hip_atomic_fetch_add(&g_root[0], 1u,
                                                   __ATOMIC_ACQ_REL, __HIP_MEMORY_SCOPE_AGENT);
            if ((int)rold == SUBG - 1) {
                __hip_atomic_store(&g_root[0], 0u, __ATOMIC_RELAXED, __HIP_MEMORY_SCOPE_AGENT);
                __hip_atomic_store(&g_sense[0], s ^ 1u, __ATOMIC_RELEASE, __HIP_MEMORY_SCOPE_AGENT);
            } else {
                while (__hip_atomic_load(&g_sense[0], __ATOMIC_ACQUIRE, __HIP_MEMORY_SCOPE_AGENT) == s)
                    __builtin_amdgcn_s_sleep(8);   // ~213 ns polls
            }
        } else {
            while (__hip_atomic_load(&g_sense[0], __ATOMIC_ACQUIRE, __HIP_MEMORY_SCOPE_AGENT) == s)
                __builtin_amdgcn_s_sleep(8);
        }
        __threadfence();   // invalidate caches: subsequent reads see other blocks' writes
    }
    __syncthreads();
}

// =====================================================================
// Fused persistent cooperative kernel: project -> minmax -> scatter -> fill
// Phases separated by the manual grid barrier above (NOT cg::grid.sync(),
// whose s_sleep(127) polling cost ~90us/sync in round 1).
// =====================================================================
__global__ void __launch_bounds__(256, 4)
k_fused(const float* __restrict__ pp, const float* __restrict__ conf,
        const float* __restrict__ pose, const float* __restrict__ Km,
        const float* __restrict__ filt,
        const int* __restrict__ hp, const int* __restrict__ wp,
        int B, int n,
        float* __restrict__ zbuf, unsigned* __restrict__ packed,
        float4* __restrict__ cr4,
        unsigned* __restrict__ pminU, unsigned* __restrict__ pmaxU,
        unsigned* __restrict__ pixwin, float* __restrict__ out)
{
    const int h = *hp, w = *wp;
    const int hw = h * w;
    const int pixTot = B * hw;
    const int npts = B * n;
    const int tid = (int)threadIdx.x;
    const int gsz = (int)(gridDim.x * blockDim.x);
    const int gtid = (int)(blockIdx.x * blockDim.x) + tid;
    const int nblk = (int)gridDim.x;

    __shared__ unsigned bmn[BMAX], bmx[BMAX];     // per-block minmax accumulators (uint-ordered)
    __shared__ unsigned fw[8];                    // wave-fold scratch
    __shared__ float sdlo[BMAX], sdhi[BMAX];
    __shared__ float s_f[72];
    __shared__ float s_in[5][20][20];
    __shared__ float s_m[5][18][18];

    if (tid < BMAX) { bmn[tid] = 0xFFFFFFFFu; bmx[tid] = 0u; }
    if (tid < 72) s_f[tid] = filt[tid];
    __syncthreads();

    // ---- Phase A0: zero pixwin (grid-stride) ----
    for (int idx = gtid; idx < pixTot; idx += gsz) pixwin[idx] = 0u;

    // ---- Phase A1: project + pack + per-block minmax partials ----
    // Loop kept wave-uniform (act mask, clamped index) so shuffles are safe.
    int iters = (npts + gsz - 1) / gsz;
    for (int it = 0; it < iters; ++it) {
        int p = gtid + it * gsz;
        bool act = p < npts;
        int pc = act ? p : (npts - 1);
        int bb = pc / n;
        int i = pc - bb * n;
        unsigned ulo = 0xFFFFFFFFu, uhi = 0u;   // neutrals for uint min/max
        if (act) {
            const float* P  = pose + (size_t)bb * 16;
            const float* km = Km   + (size_t)bb * 9;
            const float* pb = pp   + (size_t)bb * 7 * n;
            float X  = pb[0 * (size_t)n + i];
            float Y  = pb[1 * (size_t)n + i];
            float Z  = pb[2 * (size_t)n + i];
            float Wc = pb[3 * (size_t)n + i];
            float pc0 = P[0] * X + P[1] * Y + P[2]  * Z + P[3]  * Wc;
            float pc1 = P[4] * X + P[5] * Y + P[6]  * Z + P[7]  * Wc;
            float pc2 = P[8] * X + P[9] * Y + P[10] * Z + P[11] * Wc;
            float z = fabsf(pc2);
            // mirror reference op order: (pc * f) / z + c
            float xc = pc0 * km[0] / z + km[2];
            float yc = pc1 * km[4] / z + km[5];
            float xr = rintf(xc);   // round-half-even, same as jnp.round
            float yr = rintf(yc);
            float cf = conf[p];
            bool valid = (xr >= 0.0f) && (xr <= (float)(w - 1)) &&
                         (yr >= 0.0f) && (yr <= (float)(h - 1)) &&
                         (z >= ZNEAR) && (z <= ZFAR) && (cf > 0.0f);
            unsigned px = valid ? (unsigned)(int)xr : 0u;
            unsigned py = valid ? (unsigned)(int)yr : 0u;
            zbuf[p] = z;
            packed[p] = (valid ? 0x80000000u : 0u) | px | (py << 12);
            cr4[p] = make_float4(cf, pb[4 * (size_t)n + i], pb[5 * (size_t)n + i], pb[6 * (size_t)n + i]);
            float ilo = valid ? (1.0f / z) : (1.0f / 1e-10f);
            float ihi = valid ? (1.0f / z) : (1.0f / 1e10f);
            ulo = __float_as_uint(ilo);
            uhi = __float_as_uint(ihi);
        }
        // fast path: wave-uniform batch -> one LDS atomic per wave
        int bb0 = __shfl(bb, 0, 64);
        if (__all(bb == bb0)) {
            unsigned wl = wave_umin_u(ulo);
            unsigned wh = wave_umax_u(uhi);
            if ((tid & 63) == 0) { atomicMin(&bmn[bb0], wl); atomicMax(&bmx[bb0], wh); }
        } else if (act) {
            atomicMin(&bmn[bb], ulo);
            atomicMax(&bmx[bb], uhi);
        }
    }
    __syncthreads();
    if (tid < B) {
        pminU[(size_t)tid * gridDim.x + blockIdx.x] = bmn[tid];
        pmaxU[(size_t)tid * gridDim.x + blockIdx.x] = bmx[tid];
    }

    grid_bar(nblk);   // partials + zbuf/packed/cr4 + pixwin zeros visible grid-wide

    // ---- Phase B0: redundant per-block fold of partials ----
    for (int bb = 0; bb < B; ++bb) {
        unsigned lmin = 0xFFFFFFFFu, lmax = 0u;
        for (int k = tid; k < (int)gridDim.x; k += (int)blockDim.x) {
            unsigned a  = pminU[(size_t)bb * gridDim.x + k];
            unsigned b2 = pmaxU[(size_t)bb * gridDim.x + k];
            lmin = (lmin < a)  ? lmin : a;
            lmax = (lmax > b2) ? lmax : b2;
        }
        lmin = wave_umin_u(lmin);
        lmax = wave_umax_u(lmax);
        int lane = tid & 63, wid = tid >> 6;
        if (lane == 0) { fw[wid] = lmin; fw[4 + wid] = lmax; }
        __syncthreads();
        if (tid == 0) {
            unsigned m0 = fw[0]; m0 = (m0 < fw[1]) ? m0 : fw[1];
            m0 = (m0 < fw[2]) ? m0 : fw[2]; m0 = (m0 < fw[3]) ? m0 : fw[3];
            unsigned m1 = fw[4]; m1 = (m1 > fw[5]) ? m1 : fw[5];
            m1 = (m1 > fw[6]) ? m1 : fw[6]; m1 = (m1 > fw[7]) ? m1 : fw[7];
            sdlo[bb] = __uint_as_float(m0);
            sdhi[bb] = __uint_as_float(m1);
        }
        __syncthreads();
    }

    // ---- Phase B1: scatter (single atomic per point) ----
    // key = (dq<<20)|(i+1); max == (highest bin, last index). dq monotone in 1/z.
    for (int p = gtid; p < npts; p += gsz) {
        unsigned pk = packed[p];
        if (!(pk & 0x80000000u)) continue;
        int bb = p / n;
        int i = p - bb * n;
        float inv = 1.0f / zbuf[p];
        float dlo = sdlo[bb], dhi = sdhi[bb];
        int dq = (int)((inv - dlo) / (dhi - dlo) * (float)(NQ - 1));  // trunc, matches astype(int32)
        int x = (int)(pk & 0xFFFu);
        int y = (int)((pk >> 12) & 0xFFFu);
        unsigned key = ((unsigned)dq << 20) | (unsigned)(i + 1);      // needs n < 2^20
        atomicMax(&pixwin[(size_t)bb * hw + (size_t)y * w + x], key);
    }

    grid_bar(nblk);   // pixwin winners visible grid-wide

    // ---- Phase C: fused resolve + BOTH hole-fill iterations (grid-stride over exact tiles) ----
    int tilesX = (w + FT - 1) / FT;
    int tilesY = (h + FT - 1) / FT;
    int tpb = tilesX * tilesY;
    int totTiles = B * tpb;
    for (int t = (int)blockIdx.x; t < totTiles; t += (int)gridDim.x) {
        int bb = t / tpb;
        int tile = t - bb * tpb;
        int tY = tile / tilesX, tX = tile - tY * tilesX;
        int gy0 = tY * FT - 2, gx0 = tX * FT - 2;   // origin of the 20x20 halo

        for (int idx = tid; idx < 400; idx += (int)blockDim.x) {
            int yy = idx / 20, xx = idx - yy * 20;
            int gy = gy0 + yy, gx = gx0 + xx;
            float v0 = 0.0f, v1 = 0.0f, v2 = 0.0f, v3 = 0.0f, v4 = 0.0f;
            if (((unsigned)gy < (unsigned)h) && ((unsigned)gx < (unsigned)w)) {
                int ys = h - 1 - gy;            // flipped source row
                unsigned key = pixwin[(size_t)bb * hw + (size_t)ys * w + gx];
                if (key) {
                    int i = (int)(key & 0xFFFFFu) - 1;
                    size_t p = (size_t)bb * n + i;
                    v0 = zbuf[p];               // z (>0); conf>0 for winners so max(.,0) is a no-op
                    float4 cr = cr4[p];
                    v1 = cr.x; v2 = cr.y; v3 = cr.z; v4 = cr.w;
                }
            }
            s_in[0][yy][xx] = v0;   // zero-pad outside == conv 'SAME'
            s_in[1][yy][xx] = v1;
            s_in[2][yy][xx] = v2;
            s_in[3][yy][xx] = v3;
            s_in[4][yy][xx] = v4;
        }
        __syncthreads();

        // ---- iteration 1 at 18x18 positions (s_in coords 1..18) ----
        for (int idx = tid; idx < 324; idx += (int)blockDim.x) {
            int py = idx / 18, px = idx - py * 18;
            int sy = py + 1, sx = px + 1;
            int gy = gy0 + sy, gx = gx0 + sx;
            bool vc = ((unsigned)gy < (unsigned)h) && ((unsigned)gx < (unsigned)w);
            float d[9];
            #pragma unroll
            for (int tt = 0; tt < 9; ++tt) d[tt] = s_in[0][sy + tt / 3 - 1][sx + tt % 3 - 1];
            float s = 0.0f;
            #pragma unroll
            for (int tt = 0; tt < 9; ++tt) s += d[tt];
            float dc0 = d[4];
            float ov[5];
            #pragma unroll
            for (int ch = 0; ch < 5; ++ch) ov[ch] = s_in[ch][sy][sx];
            if ((s > 0.0f) && (dc0 <= 0.0f)) {
                float prod = 1.0f;
                #pragma unroll
                for (int k = 0; k < 8; ++k) {
                    float o = 0.0f;
                    #pragma unroll
                    for (int tt = 0; tt < 9; ++tt) o += s_f[k * 9 + tt] * d[tt];
                    prod *= o;
                }
                if (fabsf(prod) > 1e-10f) {
                    #pragma unroll
                    for (int ch = 0; ch < 5; ++ch) {
                        float m = -INFINITY;
                        #pragma unroll
                        for (int tt = 0; tt < 9; ++tt) {
                            int ny = gy + tt / 3 - 1, nx = gx + tt % 3 - 1;
                            if (((unsigned)ny < (unsigned)h) && ((unsigned)nx < (unsigned)w))
                                m = fmaxf(m, s_in[ch][sy + tt / 3 - 1][sx + tt % 3 - 1]);
                        }
                        ov[ch] = m;
                    }
                }
            }
            if (!vc) { ov[0] = 0.0f; ov[1] = 0.0f; ov[2] = 0.0f; ov[3] = 0.0f; ov[4] = 0.0f; }
            #pragma unroll
            for (int ch = 0; ch < 5; ++ch) s_m[ch][py][px] = ov[ch];
        }
        __syncthreads();

        // ---- iteration 2 at own pixel (16x16) ----
        int ly = tid >> 4, lx = tid & 15;
        int gy = tY * FT + ly, gx = tX * FT + lx;
        if (((unsigned)gy < (unsigned)h) && ((unsigned)gx < (unsigned)w)) {
            int sy = ly + 1, sx = lx + 1;   // coords in s_m
            float d[9];
            #pragma unroll
            for (int tt = 0; tt < 9; ++tt) d[tt] = s_m[0][sy + tt / 3 - 1][sx + tt % 3 - 1];
            float s = 0.0f;
            #pragma unroll
            for (int tt = 0; tt < 9; ++tt) s += d[tt];
            float dc0 = d[4];
            float ov[5];
            #pragma unroll
            for (int ch = 0; ch < 5; ++ch) ov[ch] = s_m[ch][sy][sx];
            if ((s > 0.0f) && (dc0 <= 0.0f)) {
                float prod = 1.0f;
                #pragma unroll
                for (int k = 0; k < 8; ++k) {
                    float o = 0.0f;
                    #pragma unroll
                    for (int tt = 0; tt < 9; ++tt) o += s_f[k * 9 + tt] * d[tt];
                    prod *= o;
                }
                if (fabsf(prod) > 1e-10f) {
                    #pragma unroll
                    for (int ch = 0; ch < 5; ++ch) {
                        float m = -INFINITY;
                        #pragma unroll
                        for (int tt = 0; tt < 9; ++tt) {
                            int ny = gy + tt / 3 - 1, nx = gx + tt % 3 - 1;
                            if (((unsigned)ny < (unsigned)h) && ((unsigned)nx < (unsigned)w))
                                m = fmaxf(m, s_m[ch][sy + tt / 3 - 1][sx + tt % 3 - 1]);
                        }
                        ov[ch] = m;
                    }
                }
            }
            size_t g = (size_t)gy * w + gx;
            out[(size_t)bb * hw + g] = ov[0];
            out[(size_t)pixTot + (size_t)bb * hw + g] = ov[1];
            size_t rb = 2 * (size_t)pixTot;
            out[rb + (((size_t)bb * 3 + 0) * hw) + g] = ov[2];
            out[rb + (((size_t)bb * 3 + 1) * hw) + g] = ov[3];
            out[rb + (((size_t)bb * 3 + 2) * hw) + g] = ov[4];
        }
        __syncthreads();   // before next tile reuses s_in/s_m
    }
}

// =====================================================================
// Fallback path: the original verified 3-kernel pipeline, launched only
// if the cooperative launch is rejected.
// =====================================================================
__global__ void k_project(const float* __restrict__ pp, const float* __restrict__ conf,
                          const float* __restrict__ pose, const float* __restrict__ Km,
                          const int* __restrict__ hp, const int* __restrict__ wp,
                          int B, int n,
                          float* __restrict__ zbuf, unsigned* __restrict__ packed,
                          float4* __restrict__ cr4,
                          float* __restrict__ pmin, float* __restrict__ pmax, int nBlk,
                          unsigned* __restrict__ pixwin, int pixTot) {
    int bb = blockIdx.y;
    int i = blockIdx.x * blockDim.x + threadIdx.x;
    size_t ztid = ((size_t)blockIdx.y * gridDim.x + blockIdx.x) * blockDim.x + threadIdx.x;
    if (ztid < (size_t)pixTot) pixwin[ztid] = 0u;

    int h = *hp, w = *wp;
    float inv_lo = INFINITY;
    float inv_hi = 0.0f;
    if (i < n) {
        const float* P  = pose + (size_t)bb * 16;
        const float* km = Km   + (size_t)bb * 9;
        const float* pb = pp   + (size_t)bb * 7 * n;
        float X  = pb[0 * (size_t)n + i];
        float Y  = pb[1 * (size_t)n + i];
        float Z  = pb[2 * (size_t)n + i];
        float Wc = pb[3 * (size_t)n + i];
        float pc0 = P[0] * X + P[1] * Y + P[2]  * Z + P[3]  * Wc;
        float pc1 = P[4] * X + P[5] * Y + P[6]  * Z + P[7]  * Wc;
        float pc2 = P[8] * X + P[9] * Y + P[10] * Z + P[11] * Wc;
        float z = fabsf(pc2);
        float xc = pc0 * km[0] / z + km[2];
        float yc = pc1 * km[4] / z + km[5];
        float xr = rintf(xc);
        float yr = rintf(yc);
        float cf = conf[(size_t)bb * n + i];
        bool valid = (xr >= 0.0f) && (xr <= (float)(w - 1)) &&
                     (yr >= 0.0f) && (yr <= (float)(h - 1)) &&
                     (z >= ZNEAR) && (z <= ZFAR) && (cf > 0.0f);
        unsigned px = valid ? (unsigned)(int)xr : 0u;
        unsigned py = valid ? (unsigned)(int)yr : 0u;
        size_t p = (size_t)bb * n + i;
        zbuf[p] = z;
        packed[p] = (valid ? 0x80000000u : 0u) | px | (py << 12);
        cr4[p] = make_float4(cf, pb[4 * (size_t)n + i], pb[5 * (size_t)n + i], pb[6 * (size_t)n + i]);
        inv_lo = valid ? (1.0f / z) : (1.0f / 1e-10f);
        inv_hi = valid ? (1.0f / z) : (1.0f / 1e10f);
    }
    __shared__ float smin[4], smax[4];
    float wmin = wave_min_f(inv_lo);
    float wmax = wave_max_f(inv_hi);
    int lane = threadIdx.x & 63, wid = threadIdx.x >> 6;
    if (lane == 0) { smin[wid] = wmin; smax[wid] = wmax; }
    __syncthreads();
    if (threadIdx.x == 0) {
        pmin[(size_t)bb * nBlk + blockIdx.x] = fminf(fminf(smin[0], smin[1]), fminf(smin[2], smin[3]));
        pmax[(size_t)bb * nBlk + blockIdx.x] = fmaxf(fmaxf(smax[0], smax[1]), fmaxf(smax[2], smax[3]));
    }
}

__global__ void k_scatter(const float* __restrict__ zbuf, const unsigned* __restrict__ packed,
                          const float* __restrict__ pminb, const float* __restrict__ pmaxb, int nBlk,
                          const int* __restrict__ hp, const int* __restrict__ wp,
                          int B, int n, unsigned* __restrict__ pixwin) {
    __shared__ float smin[4], smax[4];
    __shared__ float sdlo[8], sdhi[8];
    for (int bb = 0; bb < B; ++bb) {
        float lmin = INFINITY, lmax = 0.0f;
        for (int k = threadIdx.x; k < nBlk; k += blockDim.x) {
            lmin = fminf(lmin, pminb[(size_t)bb * nBlk + k]);
            lmax = fmaxf(lmax, pmaxb[(size_t)bb * nBlk + k]);
        }
        lmin = wave_min_f(lmin);
        lmax = wave_max_f(lmax);
        int lane = threadIdx.x & 63, wid = threadIdx.x >> 6;
        if (lane == 0) { smin[wid] = lmin; smax[wid] = lmax; }
        __syncthreads();
        if (threadIdx.x == 0) {
            sdlo[bb] = fminf(fminf(smin[0], smin[1]), fminf(smin[2], smin[3]));
            sdhi[bb] = fmaxf(fmaxf(smax[0], smax[1]), fmaxf(smax[2], smax[3]));
        }
        __syncthreads();
    }
    int p = blockIdx.x * blockDim.x + threadIdx.x;
    if (p >= B * n) return;
    unsigned pk = packed[p];
    if (!(pk & 0x80000000u)) return;
    int bb = p / n;
    int i = p - bb * n;
    float inv = 1.0f / zbuf[p];
    float dlo = sdlo[bb], dhi = sdhi[bb];
    int dq = (int)((inv - dlo) / (dhi - dlo) * (float)(NQ - 1));
    int h = *hp, w = *wp;
    int x = (int)(pk & 0xFFFu);
    int y = (int)((pk >> 12) & 0xFFFu);
    unsigned key = ((unsigned)dq << 20) | (unsigned)(i + 1);
    atomicMax(&pixwin[(size_t)bb * h * w + (size_t)y * w + x], key);
}

__global__ void k_resfill(const float* __restrict__ zbuf, const float4* __restrict__ cr4,
                          const unsigned* __restrict__ pixwin,
                          const float* __restrict__ filt,
                          const int* __restrict__ hp, const int* __restrict__ wp,
                          int B, int n, float* __restrict__ out, int pixTot) {
    int h = *hp, w = *wp;
    int tilesX = (w + FT - 1) / FT;
    int tilesY = (h + FT - 1) / FT;
    int tile = blockIdx.x;
    if (tile >= tilesX * tilesY) return;
    int bb = blockIdx.y;
    int tY = tile / tilesX, tX = tile - tY * tilesX;
    int gy0 = tY * FT - 2, gx0 = tX * FT - 2;
    int hw = h * w;

    __shared__ float s_f[72];
    __shared__ float s_in[5][20][20];
    __shared__ float s_m[5][18][18];
    int tid = threadIdx.x;
    if (tid < 72) s_f[tid] = filt[tid];

    for (int idx = tid; idx < 400; idx += blockDim.x) {
        int yy = idx / 20, xx = idx - yy * 20;
        int gy = gy0 + yy, gx = gx0 + xx;
        float v0 = 0.0f, v1 = 0.0f, v2 = 0.0f, v3 = 0.0f, v4 = 0.0f;
        if (((unsigned)gy < (unsigned)h) && ((unsigned)gx < (unsigned)w)) {
            int ys = h - 1 - gy;
            unsigned key = pixwin[(size_t)bb * hw + (size_t)ys * w + gx];
            if (key) {
                int i = (int)(key & 0xFFFFFu) - 1;
                size_t p = (size_t)bb * n + i;
                v0 = zbuf[p];
                float4 cr = cr4[p];
                v1 = cr.x; v2 = cr.y; v3 = cr.z; v4 = cr.w;
            }
        }
        s_in[0][yy][xx] = v0;
        s_in[1][yy][xx] = v1;
        s_in[2][yy][xx] = v2;
        s_in[3][yy][xx] = v3;
        s_in[4][yy][xx] = v4;
    }
    __syncthreads();

    for (int idx = tid; idx < 324; idx += blockDim.x) {
        int py = idx / 18, px = idx - py * 18;
        int sy = py + 1, sx = px + 1;
        int gy = gy0 + sy, gx = gx0 + sx;
        bool vc = ((unsigned)gy < (unsigned)h) && ((unsigned)gx < (unsigned)w);
        float d[9];
        #pragma unroll
        for (int t = 0; t < 9; ++t) d[t] = s_in[0][sy + t / 3 - 1][sx + t % 3 - 1];
        float s = 0.0f;
        #pragma unroll
        for (int t = 0; t < 9; ++t) s += d[t];
        float dc0 = d[4];
        float ov[5];
        #pragma unroll
        for (int ch = 0; ch < 5; ++ch) ov[ch] = s_in[ch][sy][sx];
        if ((s > 0.0f) && (dc0 <= 0.0f)) {
            float prod = 1.0f;
            #pragma unroll
            for (int k = 0; k < 8; ++k) {
                float o = 0.0f;
                #pragma unroll
                for (int t = 0; t < 9; ++t) o += s_f[k * 9 + t] * d[t];
                prod *= o;
            }
            if (fabsf(prod) > 1e-10f) {
                #pragma unroll
                for (int ch = 0; ch < 5; ++ch) {
                    float m = -INFINITY;
                    #pragma unroll
                    for (int t = 0; t < 9; ++t) {
                        int ny = gy + t / 3 - 1, nx = gx + t % 3 - 1;
                        if (((unsigned)ny < (unsigned)h) && ((unsigned)nx < (unsigned)w))
                            m = fmaxf(m, s_in[ch][sy + t / 3 - 1][sx + t % 3 - 1]);
                    }
                    ov[ch] = m;
                }
            }
        }
        if (!vc) { ov[0] = 0.0f; ov[1] = 0.0f; ov[2] = 0.0f; ov[3] = 0.0f; ov[4] = 0.0f; }
        #pragma unroll
        for (int ch = 0; ch < 5; ++ch) s_m[ch][py][px] = ov[ch];
    }
    __syncthreads();

    int ly = tid >> 4, lx = tid & 15;
    int gy = tY * FT + ly, gx = tX * FT + lx;
    if (((unsigned)gy < (unsigned)h) && ((unsigned)gx < (unsigned)w)) {
        int sy = ly + 1, sx = lx + 1;
        float d[9];
        #pragma unroll
        for (int t = 0; t < 9; ++t) d[t] = s_m[0][sy + t / 3 - 1][sx + t % 3 - 1];
        float s = 0.0f;
        #pragma unroll
        for (int t = 0; t < 9; ++t) s += d[t];
        float dc0 = d[4];
        float ov[5];
        #pragma unroll
        for (int ch = 0; ch < 5; ++ch) ov[ch] = s_m[ch][sy][sx];
        if ((s > 0.0f) && (dc0 <= 0.0f)) {
            float prod = 1.0f;
            #pragma unroll
            for (int k = 0; k < 8; ++k) {
                float o = 0.0f;
                #pragma unroll
                for (int t = 0; t < 9; ++t) o += s_f[k * 9 + t] * d[t];
                prod *= o;
            }
            if (fabsf(prod) > 1e-10f) {
                #pragma unroll
                for (int ch = 0; ch < 5; ++ch) {
                    float m = -INFINITY;
                    #pragma unroll
                    for (int t = 0; t < 9; ++t) {
                        int ny = gy + t / 3 - 1, nx = gx + t % 3 - 1;
                        if (((unsigned)ny < (unsigned)h) && ((unsigned)nx < (unsigned)w))
                            m = fmaxf(m, s_m[ch][sy + t / 3 - 1][sx + t % 3 - 1]);
                    }
                    ov[ch] = m;
                }
            }
        }
        size_t g = (size_t)gy * w + gx;
        out[(size_t)bb * hw + g] = ov[0];
        out[(size_t)pixTot + (size_t)bb * hw + g] = ov[1];
        size_t rb = 2 * (size_t)pixTot;
        out[rb + (((size_t)bb * 3 + 0) * hw) + g] = ov[2];
        out[rb + (((size_t)bb * 3 + 1) * hw) + g] = ov[3];
        out[rb + (((size_t)bb * 3 + 2) * hw) + g] = ov[4];
    }
}

static inline size_t align16(size_t x) { return (x + 15) & ~(size_t)15; }

extern "C" void kernel_launch(void* const* d_in, const int* in_sizes, int n_in,
                              void* d_out, int out_size, void* d_ws, size_t ws_size,
                              hipStream_t stream) {
    const float* pp   = (const float*)d_in[0];
    const float* conf = (const float*)d_in[1];
    const float* pose = (const float*)d_in[2];
    const float* Km   = (const float*)d_in[3];
    const float* filt = (const float*)d_in[4];
    const int*   hp   = (const int*)d_in[5];
    const int*   wp   = (const int*)d_in[6];

    int B = in_sizes[2] / 16;          // pose is [B,4,4]
    int n = in_sizes[1] / B;           // conf is [B,n]
    size_t pix = (size_t)out_size / 5; // B*h*w  (out = depth + conf + 3*rgb)
    size_t npts = (size_t)B * n;

    const int bs = 256;
    int nBlk = (n + bs - 1) / bs;

    char* ws = (char*)d_ws;
    size_t off = 0;
    unsigned* pixwin = (unsigned*)(ws + off);  off = align16(off + pix * 4);
    float* zbuf   = (float*)(ws + off);        off = align16(off + npts * 4);
    unsigned* packed = (unsigned*)(ws + off);  off = align16(off + npts * 4);
    float4* cr4   = (float4*)(ws + off);       off = align16(off + npts * 16);
    unsigned* pminU = (unsigned*)(ws + off);   off = align16(off + (size_t)GMAX * BMAX * 4);
    unsigned* pmaxU = (unsigned*)(ws + off);   off = align16(off + (size_t)GMAX * BMAX * 4);

    float* out = (float*)d_out;
    int pixI = (int)pix;

    {
        void* kargs[] = { (void*)&pp, (void*)&conf, (void*)&pose, (void*)&Km, (void*)&filt,
                          (void*)&hp, (void*)&wp, (void*)&B, (void*)&n,
                          (void*)&zbuf, (void*)&packed, (void*)&cr4,
                          (void*)&pminU, (void*)&pmaxU, (void*)&pixwin, (void*)&out };
        hipError_t e = hipLaunchCooperativeKernel((const void*)k_fused, dim3(GRID), dim3(bs),
                                                  kargs, 0, stream);
        if (e == hipSuccess) return;
    }

    // ---------- fallback: verified 3-kernel path ----------
    float* pminb = (float*)pminU;
    float* pmaxb = (float*)pmaxU;
    size_t hw = pix / B;

    dim3 gproj(nBlk, B);
    k_project<<<gproj, bs, 0, stream>>>(pp, conf, pose, Km, hp, wp, B, n,
                                        zbuf, packed, cr4, pminb, pmaxb, nBlk,
                                        pixwin, pixI);

    int nptsI = (int)npts;
    k_scatter<<<(nptsI + bs - 1) / bs, bs, 0, stream>>>(zbuf, packed, pminb, pmaxb, nBlk,
                                                        hp, wp, B, n, pixwin);

    size_t tileBound = hw / (FT * FT) + hw / FT + 2;
    dim3 gfill((unsigned)tileBound, B);
    k_resfill<<<gfill, bs, 0, stream>>>(zbuf, cr4, pixwin, filt, hp, wp, B, n, out, pixI);
}

// Round 3
// 102.136 us; speedup vs baseline: 2.6994x; 2.6994x over previous
//
#include <hip/hip_runtime.h>
#include <stdint.h>

#define NQ 64
#define ZNEAR 0.1f
#define ZFAR 1000.0f
#define FT 16   // fill tile

// ---------------- wave reductions (64-lane) ----------------
__device__ __forceinline__ float wave_min_f(float v) {
    #pragma unroll
    for (int off = 1; off < 64; off <<= 1)
        v = fminf(v, __shfl_xor(v, off, 64));
    return v;
}
__device__ __forceinline__ float wave_max_f(float v) {
    #pragma unroll
    for (int off = 1; off < 64; off <<= 1)
        v = fmaxf(v, __shfl_xor(v, off, 64));
    return v;
}

// ---------------- K1: project + pack + per-block min/max partials + pixwin zero + cr4 ----------
// pz[p] = { flags|x|y<<12 , float_bits(z) }  -- one 8B store replaces zbuf+packed.
// cr4[p] = (conf, r, g, b) -> single-line winner gather in k_resfill.
__global__ void k_project(const float* __restrict__ pp, const float* __restrict__ conf,
                          const float* __restrict__ pose, const float* __restrict__ Km,
                          const int* __restrict__ hp, const int* __restrict__ wp,
                          int B, int n,
                          uint2* __restrict__ pz, float4* __restrict__ cr4,
                          float* __restrict__ pmin, float* __restrict__ pmax, int nBlk,
                          unsigned long long* __restrict__ pixwin, int pixTot) {
    int bb = blockIdx.y;
    int i = blockIdx.x * blockDim.x + threadIdx.x;
    // fused pixwin zeroing (grid covers B*n >= pixTot threads)
    size_t ztid = ((size_t)blockIdx.y * gridDim.x + blockIdx.x) * blockDim.x + threadIdx.x;
    if (ztid < (size_t)pixTot) pixwin[ztid] = 0ull;

    int h = *hp, w = *wp;
    float inv_lo = INFINITY;   // neutral for min
    float inv_hi = 0.0f;       // neutral for max
    if (i < n) {
        const float* P  = pose + (size_t)bb * 16;
        const float* km = Km   + (size_t)bb * 9;
        const float* pb = pp   + (size_t)bb * 7 * n;
        float X  = pb[0 * (size_t)n + i];
        float Y  = pb[1 * (size_t)n + i];
        float Z  = pb[2 * (size_t)n + i];
        float Wc = pb[3 * (size_t)n + i];
        float pc0 = P[0] * X + P[1] * Y + P[2]  * Z + P[3]  * Wc;
        float pc1 = P[4] * X + P[5] * Y + P[6]  * Z + P[7]  * Wc;
        float pc2 = P[8] * X + P[9] * Y + P[10] * Z + P[11] * Wc;
        float z = fabsf(pc2);
        // mirror reference op order: (pc * f) / z + c
        float xc = pc0 * km[0] / z + km[2];
        float yc = pc1 * km[4] / z + km[5];
        float xr = rintf(xc);   // round-half-even, same as jnp.round
        float yr = rintf(yc);
        float cf = conf[(size_t)bb * n + i];
        bool valid = (xr >= 0.0f) && (xr <= (float)(w - 1)) &&
                     (yr >= 0.0f) && (yr <= (float)(h - 1)) &&
                     (z >= ZNEAR) && (z <= ZFAR) && (cf > 0.0f);
        unsigned px = valid ? (unsigned)(int)xr : 0u;
        unsigned py = valid ? (unsigned)(int)yr : 0u;
        size_t p = (size_t)bb * n + i;
        pz[p] = make_uint2((valid ? 0x80000000u : 0u) | px | (py << 12), __float_as_uint(z));
        cr4[p] = make_float4(cf, pb[4 * (size_t)n + i], pb[5 * (size_t)n + i], pb[6 * (size_t)n + i]);
        inv_lo = valid ? (1.0f / z) : (1.0f / 1e-10f);
        inv_hi = valid ? (1.0f / z) : (1.0f / 1e10f);
    }
    __shared__ float smin[4], smax[4];
    float wmin = wave_min_f(inv_lo);
    float wmax = wave_max_f(inv_hi);
    int lane = threadIdx.x & 63, wid = threadIdx.x >> 6;
    if (lane == 0) { smin[wid] = wmin; smax[wid] = wmax; }
    __syncthreads();
    if (threadIdx.x == 0) {
        pmin[(size_t)bb * nBlk + blockIdx.x] = fminf(fminf(smin[0], smin[1]), fminf(smin[2], smin[3]));
        pmax[(size_t)bb * nBlk + blockIdx.x] = fmaxf(fmaxf(smax[0], smax[1]), fmaxf(smax[2], smax[3]));
    }
}

// ---------------- K2: inline minmax fold + single-atomic composite ----------------
// key64 = ((dq<<20)|(i+1)) << 32 | z_bits. Lexicographic order = (dq, i) since i is
// unique (z bits never tie-break); max == (highest bin, last index). dq is monotone
// non-decreasing in 1/z, so the winner's z matches the reference composite, and the
// resolve step reads z straight out of the key (no zbuf gather).
__global__ void k_scatter(const uint2* __restrict__ pz,
                          const float* __restrict__ pminb, const float* __restrict__ pmaxb, int nBlk,
                          const int* __restrict__ hp, const int* __restrict__ wp,
                          int B, int n, unsigned long long* __restrict__ pixwin) {
    __shared__ float smin[4], smax[4];
    __shared__ float sdlo[8], sdhi[8];   // B <= 8
    // redundant per-block fold of the per-block partials (coalesced, L2-resident)
    for (int bb = 0; bb < B; ++bb) {
        float lmin = INFINITY, lmax = 0.0f;
        for (int k = threadIdx.x; k < nBlk; k += blockDim.x) {
            lmin = fminf(lmin, pminb[(size_t)bb * nBlk + k]);
            lmax = fmaxf(lmax, pmaxb[(size_t)bb * nBlk + k]);
        }
        lmin = wave_min_f(lmin);
        lmax = wave_max_f(lmax);
        int lane = threadIdx.x & 63, wid = threadIdx.x >> 6;
        if (lane == 0) { smin[wid] = lmin; smax[wid] = lmax; }
        __syncthreads();
        if (threadIdx.x == 0) {
            sdlo[bb] = fminf(fminf(smin[0], smin[1]), fminf(smin[2], smin[3]));
            sdhi[bb] = fmaxf(fmaxf(smax[0], smax[1]), fmaxf(smax[2], smax[3]));
        }
        __syncthreads();
    }
    int p = blockIdx.x * blockDim.x + threadIdx.x;
    if (p >= B * n) return;
    uint2 v = pz[p];
    unsigned pk = v.x;
    if (!(pk & 0x80000000u)) return;
    int bb = p / n;
    int i = p - bb * n;
    float z = __uint_as_float(v.y);
    float inv = 1.0f / z;
    float dlo = sdlo[bb], dhi = sdhi[bb];
    int dq = (int)((inv - dlo) / (dhi - dlo) * (float)(NQ - 1));  // trunc, matches astype(int32)
    int h = *hp, w = *wp;
    int x = (int)(pk & 0xFFFu);
    int y = (int)((pk >> 12) & 0xFFFu);
    unsigned key32 = ((unsigned)dq << 20) | (unsigned)(i + 1);    // needs n < 2^20
    unsigned long long key = ((unsigned long long)key32 << 32) | (unsigned long long)v.y;
    atomicMax(&pixwin[(size_t)bb * h * w + (size_t)y * w + x], key);
}

// ---------------- K3: fused resolve + BOTH hole-fill iterations ----------------
// Grid-strided over the EXACT device-computed tile count (no dummy blocks).
// Halo load resolves winners directly from pixwin at the flipped row (h-1-gy):
// z comes from the key itself; only cr4 needs a gather.
__global__ void k_resfill(const float4* __restrict__ cr4,
                          const unsigned long long* __restrict__ pixwin,
                          const float* __restrict__ filt,
                          const int* __restrict__ hp, const int* __restrict__ wp,
                          int B, int n, float* __restrict__ out, int pixTot) {
    int h = *hp, w = *wp;
    int hw = h * w;
    int tilesX = (w + FT - 1) / FT;
    int tilesY = (h + FT - 1) / FT;
    int tpb = tilesX * tilesY;
    int totTiles = B * tpb;
    int tid = threadIdx.x;

    __shared__ float s_f[72];
    __shared__ float s_in[5][20][20];
    __shared__ float s_m[5][18][18];
    if (tid < 72) s_f[tid] = filt[tid];

    for (int t = (int)blockIdx.x; t < totTiles; t += (int)gridDim.x) {
        int bb = t / tpb;
        int tile = t - bb * tpb;
        int tY = tile / tilesX, tX = tile - tY * tilesX;
        int gy0 = tY * FT - 2, gx0 = tX * FT - 2;   // origin of the 20x20 halo

        for (int idx = tid; idx < 400; idx += (int)blockDim.x) {
            int yy = idx / 20, xx = idx - yy * 20;
            int gy = gy0 + yy, gx = gx0 + xx;
            float v0 = 0.0f, v1 = 0.0f, v2 = 0.0f, v3 = 0.0f, v4 = 0.0f;
            if (((unsigned)gy < (unsigned)h) && ((unsigned)gx < (unsigned)w)) {
                int ys = h - 1 - gy;            // flipped source row
                unsigned long long key = pixwin[(size_t)bb * hw + (size_t)ys * w + gx];
                if (key) {
                    int i = (int)((unsigned)(key >> 32) & 0xFFFFFu) - 1;
                    size_t p = (size_t)bb * n + i;
                    v0 = __uint_as_float((unsigned)(key & 0xFFFFFFFFull));  // z (>0)
                    float4 cr = cr4[p];         // conf>0 for winners so max(.,0) is a no-op
                    v1 = cr.x; v2 = cr.y; v3 = cr.z; v4 = cr.w;
                }
            }
            s_in[0][yy][xx] = v0;   // zero-pad outside == conv 'SAME'
            s_in[1][yy][xx] = v1;
            s_in[2][yy][xx] = v2;
            s_in[3][yy][xx] = v3;
            s_in[4][yy][xx] = v4;
        }
        __syncthreads();

        // ---- iteration 1 at 18x18 positions (s_in coords 1..18) ----
        for (int idx = tid; idx < 324; idx += (int)blockDim.x) {
            int py = idx / 18, px = idx - py * 18;
            int sy = py + 1, sx = px + 1;
            int gy = gy0 + sy, gx = gx0 + sx;
            bool vc = ((unsigned)gy < (unsigned)h) && ((unsigned)gx < (unsigned)w);
            float d[9];
            #pragma unroll
            for (int tt = 0; tt < 9; ++tt) d[tt] = s_in[0][sy + tt / 3 - 1][sx + tt % 3 - 1];
            float s = 0.0f;
            #pragma unroll
            for (int tt = 0; tt < 9; ++tt) s += d[tt];
            float dc0 = d[4];
            float ov[5];
            #pragma unroll
            for (int ch = 0; ch < 5; ++ch) ov[ch] = s_in[ch][sy][sx];
            if ((s > 0.0f) && (dc0 <= 0.0f)) {
                float prod = 1.0f;
                #pragma unroll
                for (int k = 0; k < 8; ++k) {
                    float o = 0.0f;
                    #pragma unroll
                    for (int tt = 0; tt < 9; ++tt) o += s_f[k * 9 + tt] * d[tt];
                    prod *= o;
                }
                if (fabsf(prod) > 1e-10f) {
                    #pragma unroll
                    for (int ch = 0; ch < 5; ++ch) {
                        float m = -INFINITY;
                        #pragma unroll
                        for (int tt = 0; tt < 9; ++tt) {
                            int ny = gy + tt / 3 - 1, nx = gx + tt % 3 - 1;
                            if (((unsigned)ny < (unsigned)h) && ((unsigned)nx < (unsigned)w))
                                m = fmaxf(m, s_in[ch][sy + tt / 3 - 1][sx + tt % 3 - 1]);
                        }
                        ov[ch] = m;
                    }
                }
            }
            if (!vc) { ov[0] = 0.0f; ov[1] = 0.0f; ov[2] = 0.0f; ov[3] = 0.0f; ov[4] = 0.0f; }
            #pragma unroll
            for (int ch = 0; ch < 5; ++ch) s_m[ch][py][px] = ov[ch];
        }
        __syncthreads();

        // ---- iteration 2 at own pixel (16x16) ----
        int ly = tid >> 4, lx = tid & 15;
        int gy = tY * FT + ly, gx = tX * FT + lx;
        if (((unsigned)gy < (unsigned)h) && ((unsigned)gx < (unsigned)w)) {
            int sy = ly + 1, sx = lx + 1;   // coords in s_m
            float d[9];
            #pragma unroll
            for (int tt = 0; tt < 9; ++tt) d[tt] = s_m[0][sy + tt / 3 - 1][sx + tt % 3 - 1];
            float s = 0.0f;
            #pragma unroll
            for (int tt = 0; tt < 9; ++tt) s += d[tt];
            float dc0 = d[4];
            float ov[5];
            #pragma unroll
            for (int ch = 0; ch < 5; ++ch) ov[ch] = s_m[ch][sy][sx];
            if ((s > 0.0f) && (dc0 <= 0.0f)) {
                float prod = 1.0f;
                #pragma unroll
                for (int k = 0; k < 8; ++k) {
                    float o = 0.0f;
                    #pragma unroll
                    for (int tt = 0; tt < 9; ++tt) o += s_f[k * 9 + tt] * d[tt];
                    prod *= o;
                }
                if (fabsf(prod) > 1e-10f) {
                    #pragma unroll
                    for (int ch = 0; ch < 5; ++ch) {
                        float m = -INFINITY;
                        #pragma unroll
                        for (int tt = 0; tt < 9; ++tt) {
                            int ny = gy + tt / 3 - 1, nx = gx + tt % 3 - 1;
                            if (((unsigned)ny < (unsigned)h) && ((unsigned)nx < (unsigned)w))
                                m = fmaxf(m, s_m[ch][sy + tt / 3 - 1][sx + tt % 3 - 1]);
                        }
                        ov[ch] = m;
                    }
                }
            }
            size_t g = (size_t)gy * w + gx;
            out[(size_t)bb * hw + g] = ov[0];
            out[(size_t)pixTot + (size_t)bb * hw + g] = ov[1];
            size_t rb = 2 * (size_t)pixTot;
            out[rb + (((size_t)bb * 3 + 0) * hw) + g] = ov[2];
            out[rb + (((size_t)bb * 3 + 1) * hw) + g] = ov[3];
            out[rb + (((size_t)bb * 3 + 2) * hw) + g] = ov[4];
        }
        __syncthreads();   // before next tile reuses s_in/s_m
    }
}

static inline size_t align16(size_t x) { return (x + 15) & ~(size_t)15; }

extern "C" void kernel_launch(void* const* d_in, const int* in_sizes, int n_in,
                              void* d_out, int out_size, void* d_ws, size_t ws_size,
                              hipStream_t stream) {
    const float* pp   = (const float*)d_in[0];
    const float* conf = (const float*)d_in[1];
    const float* pose = (const float*)d_in[2];
    const float* Km   = (const float*)d_in[3];
    const float* filt = (const float*)d_in[4];
    const int*   hp   = (const int*)d_in[5];
    const int*   wp   = (const int*)d_in[6];

    int B = in_sizes[2] / 16;          // pose is [B,4,4]
    int n = in_sizes[1] / B;           // conf is [B,n]
    size_t pix = (size_t)out_size / 5; // B*h*w  (out = depth + conf + 3*rgb)
    size_t npts = (size_t)B * n;
    size_t hw = pix / B;               // h*w (host doesn't know h,w separately)

    const int bs = 256;
    int nBlk = (n + bs - 1) / bs;

    char* ws = (char*)d_ws;
    size_t off = 0;
    unsigned long long* pixwin = (unsigned long long*)(ws + off);  off = align16(off + pix * 8);
    uint2* pz     = (uint2*)(ws + off);        off = align16(off + npts * 8);
    float4* cr4   = (float4*)(ws + off);       off = align16(off + npts * 16);
    float* pminb  = (float*)(ws + off);        off = align16(off + (size_t)B * nBlk * 4);
    float* pmaxb  = (float*)(ws + off);        off = align16(off + (size_t)B * nBlk * 4);

    float* out = (float*)d_out;
    int pixI = (int)pix;

    dim3 gproj(nBlk, B);
    k_project<<<gproj, bs, 0, stream>>>(pp, conf, pose, Km, hp, wp, B, n,
                                        pz, cr4, pminb, pmaxb, nBlk,
                                        pixwin, pixI);

    int nptsI = (int)npts;
    k_scatter<<<(nptsI + bs - 1) / bs, bs, 0, stream>>>(pz, pminb, pmaxb, nBlk,
                                                        hp, wp, B, n, pixwin);

    // grid-stride over exact device-computed tile count; size for the common
    // near-square case (hw/256 tiles/batch + margin), correct for ANY h,w split.
    long long G = (long long)B * (long long)(hw / (FT * FT)) + 128;
    if (G > 2048) G = 2048;
    if (G < 64) G = 64;
    k_resfill<<<dim3((unsigned)G), bs, 0, stream>>>(cr4, pixwin, filt, hp, wp, B, n, out, pixI);
}